// Round 7
// baseline (216.966 us; speedup 1.0000x reference)
//
#include <hip/hip_runtime.h>

#define HH 64
#define WW 64
#define S  68          // padded LDS row stride (floats)
#define PH 66          // padded rows (1-px zero frame)
#define NLQ 10
#define NR 8           // rows per thread (512 threads = 8 waves = 2/SIMD)

// One block per image (grid=256 = 1 block/CU). Thread t: column x=t&63, rows
// y0..y0+7.
//
// Weight-residency war (90 uniform transition weights vs register files):
//  R1  (110us): LDS-staged -> AGPR demotion -> 720 v_accvgpr_read/step.
//  R9  (940us): asm "a"-pinning -> SCRATCH. Never.
//  R10 (122us): per-step LDS re-read -> LDS pipe binds.
//  R11 (148us): per-step global re-read -> barrier blocks hoisting.
//  R12 (103us): f32x2 pk pairs -> uniform vectors materialize in VGPRs ->
//               AGPR demotion again; VALUBusy 60%.
//  R13 (170us): readfirstlane x180 -> SGPR file (~102) overflow -> spills.
//  R14 (this): LANE-DISTRIBUTED weights. All 90 live in 2 VGPRs (lane i of
//      wtA = wtr[i]; lanes 0-25 of wtB = wtr[64+i]). Per channel l, extract
//      its 9 weights with v_readlane_b32 (imm lane -> SGPR dst, 1 VALU op).
//      Only 9 SGPRs live at a time; no LDS pipe, no barrier interaction,
//      no SGPR overflow. Register diet: q0r[80]+win[30]+m[8]+2 ~= 125 fits
//      the 128 arch budget -> demotion bloat gone. asm volatile prevents
//      LICM re-hoisting 90 invariant readlanes into SGPRs (R13 mode).
//      Cost: 90 readlanes/step (~10% of stream) buys back everything else.

__device__ __forceinline__ float rl(float v, int lane) {
  int r;
  asm volatile("v_readlane_b32 %0, %1, %2"
               : "=s"(r) : "v"(__float_as_int(v)), "i"(lane));
  return __int_as_float(r);
}

__global__ __launch_bounds__(512)
__attribute__((amdgpu_waves_per_eu(2, 2)))
void vin_fused(
    const float* __restrict__ X,    // [B,2,64,64]
    const float* __restrict__ Wh,   // [150,2,3,3]
    const float* __restrict__ bh,   // [150]
    const float* __restrict__ Wr,   // [150]
    const float* __restrict__ Wq,   // [10,1,3,3]
    const float* __restrict__ wtr,  // [10,1,3,3] transition
    const float* __restrict__ Wc,   // [4096]
    const float* __restrict__ bc,   // [1]
    float* __restrict__ out)        // [256 critic] ++ [256*40960 q]
{
  __shared__ float vb[2][PH * S];
  __shared__ float rb[PH * S];
  __shared__ float Wef[19];
  __shared__ float Wpart[152];
  __shared__ float red[8];

  const int b  = blockIdx.x;
  const int t  = threadIdx.x;
  const int x  = t & 63;
  const int lane = t & 63;
  const int yg = t >> 6;
  const int y0 = yg * NR;
  const int base0 = y0 * S + x;   // top-left of 3x3 window for row y0 (padded)

  // ---- lane-distributed weight registers (2 VGPRs per array) ----
  const float wtA = wtr[lane];
  const float wtB = (lane < 26) ? wtr[64 + lane] : 0.f;
  const float wqA = Wq[lane];
  const float wqB = (lane < 26) ? Wq[64 + lane] : 0.f;

  // ---- zero LDS (frames must be 0; interiors overwritten) ----
  {
    float* vbf = &vb[0][0];
    for (int i = t; i < 2 * PH * S; i += 512) vbf[i] = 0.f;
    for (int i = t; i < PH * S; i += 512) rb[i] = 0.f;
  }
  __syncthreads();

  // ---- stage X into vb interiors; collapse 150-ch conv to Wef[19] ----
  const float* Xb = X + (size_t)b * (2 * HH * WW);
  for (int i = t; i < HH * WW; i += 512) {
    const int yy = i >> 6, xx = i & 63;
    vb[0][(yy + 1) * S + xx + 1] = Xb[i];
    vb[1][(yy + 1) * S + xx + 1] = Xb[HH * WW + i];
  }
  if (t < 152) {                       // parallel collapse: 19 outputs x 8 parts
    const int i = t >> 3, part = t & 7;
    float s = 0.f;
    if (i < 18) {
      for (int c = part; c < 150; c += 8) s += Wr[c] * Wh[c * 18 + i];
    } else {
      for (int c = part; c < 150; c += 8) s += Wr[c] * bh[c];
    }
    Wpart[t] = s;
  }
  __syncthreads();
  if (t < 19) {
    float s = 0.f;
#pragma unroll
    for (int k = 0; k < 8; ++k) s += Wpart[t * 8 + k];
    Wef[t] = s;
  }
  __syncthreads();

  // ---- r = conv(X, Weff, pad=1) + beff -> rb ----
  {
    float We[19];
#pragma unroll
    for (int i = 0; i < 19; ++i) We[i] = Wef[i];
#pragma unroll
    for (int j = 0; j < NR; ++j) {
      const int tb = base0 + j * S;
      float s = We[18];
#pragma unroll
      for (int dy = 0; dy < 3; ++dy)
#pragma unroll
        for (int dx = 0; dx < 3; ++dx) {
          const int idx = tb + dy * S + dx;
          s = fmaf(vb[0][idx], We[dy * 3 + dx], s);
          s = fmaf(vb[1][idx], We[9 + dy * 3 + dx], s);
        }
      rb[tb + S + 1] = s;
    }
  }
  __syncthreads();

  // ---- q0 = conv(r, Wq, pad=1) -> q0r regs; v_init = max_l q0 -> vb[0] ----
  float q0r[NR][NLQ];
  {
    float win[NR + 2][3];
#pragma unroll
    for (int rr = 0; rr < NR + 2; ++rr) {
      const int a = base0 + rr * S;
      win[rr][0] = rb[a];
      win[rr][1] = rb[a + 1];
      win[rr][2] = rb[a + 2];
    }
    float m[NR];
#pragma unroll
    for (int l = 0; l < NLQ; ++l) {
      float w[9];
#pragma unroll
      for (int k = 0; k < 9; ++k) {
        const int idx = l * 9 + k;
        w[k] = (idx < 64) ? rl(wqA, idx) : rl(wqB, idx - 64);
      }
#pragma unroll
      for (int j = 0; j < NR; ++j) {
        float s;
        s = fmaf(w[0], win[j][0],     0.f);
        s = fmaf(w[1], win[j][1],     s);
        s = fmaf(w[2], win[j][2],     s);
        s = fmaf(w[3], win[j + 1][0], s);
        s = fmaf(w[4], win[j + 1][1], s);
        s = fmaf(w[5], win[j + 1][2], s);
        s = fmaf(w[6], win[j + 2][0], s);
        s = fmaf(w[7], win[j + 2][1], s);
        s = fmaf(w[8], win[j + 2][2], s);
        q0r[j][l] = s;
        m[j] = (l == 0) ? s : fmaxf(m[j], s);
      }
    }
#pragma unroll
    for (int j = 0; j < NR; ++j) vb[0][base0 + (j + 1) * S + 1] = m[j];
  }
  __syncthreads();

  // ---- K-loop: q = q0 + conv(v, w); v = max_ch(q) ----
  auto step = [&](const float* __restrict__ vin, float* __restrict__ vout) {
    float win[NR + 2][3];
#pragma unroll
    for (int rr = 0; rr < NR + 2; ++rr) {
      const int a = base0 + rr * S;
      win[rr][0] = vin[a];
      win[rr][1] = vin[a + 1];
      win[rr][2] = vin[a + 2];
    }
    float m[NR];
#pragma unroll
    for (int l = 0; l < NLQ; ++l) {
      float w[9];
#pragma unroll
      for (int k = 0; k < 9; ++k) {
        const int idx = l * 9 + k;
        w[k] = (idx < 64) ? rl(wtA, idx) : rl(wtB, idx - 64);
      }
#pragma unroll
      for (int j = 0; j < NR; ++j) {
        float s = q0r[j][l];
        s = fmaf(w[0], win[j][0],     s);
        s = fmaf(w[1], win[j][1],     s);
        s = fmaf(w[2], win[j][2],     s);
        s = fmaf(w[3], win[j + 1][0], s);
        s = fmaf(w[4], win[j + 1][1], s);
        s = fmaf(w[5], win[j + 1][2], s);
        s = fmaf(w[6], win[j + 2][0], s);
        s = fmaf(w[7], win[j + 2][1], s);
        s = fmaf(w[8], win[j + 2][2], s);
        m[j] = (l == 0) ? s : fmaxf(m[j], s);
      }
    }
#pragma unroll
    for (int j = 0; j < NR; ++j) vout[base0 + (j + 1) * S + 1] = m[j];
    __syncthreads();
  };

#pragma unroll 1
  for (int s2 = 0; s2 < 19; ++s2) { step(vb[0], vb[1]); step(vb[1], vb[0]); }
  step(vb[0], vb[1]);   // it = 38: reads vb[0], writes vb[1]

  // ---- final iteration (it=39): emit q + critic dot ----
  float wcv[NR];
#pragma unroll
  for (int j = 0; j < NR; ++j) wcv[j] = Wc[(y0 + j) * WW + x];

  float* qo = out + 256 + (size_t)b * (NLQ * HH * WW) + y0 * WW + x;
  float acc_c = 0.f;
  {
    const float* vin = vb[1];
    float win[NR + 2][3];
#pragma unroll
    for (int rr = 0; rr < NR + 2; ++rr) {
      const int a = base0 + rr * S;
      win[rr][0] = vin[a];
      win[rr][1] = vin[a + 1];
      win[rr][2] = vin[a + 2];
    }
    float m[NR];
#pragma unroll
    for (int l = 0; l < NLQ; ++l) {
      float w[9];
#pragma unroll
      for (int k = 0; k < 9; ++k) {
        const int idx = l * 9 + k;
        w[k] = (idx < 64) ? rl(wtA, idx) : rl(wtB, idx - 64);
      }
#pragma unroll
      for (int j = 0; j < NR; ++j) {
        float s = q0r[j][l];
        s = fmaf(w[0], win[j][0],     s);
        s = fmaf(w[1], win[j][1],     s);
        s = fmaf(w[2], win[j][2],     s);
        s = fmaf(w[3], win[j + 1][0], s);
        s = fmaf(w[4], win[j + 1][1], s);
        s = fmaf(w[5], win[j + 1][2], s);
        s = fmaf(w[6], win[j + 2][0], s);
        s = fmaf(w[7], win[j + 2][1], s);
        s = fmaf(w[8], win[j + 2][2], s);
        qo[l * (HH * WW) + j * WW] = s;
        m[j] = (l == 0) ? s : fmaxf(m[j], s);
      }
    }
#pragma unroll
    for (int j = 0; j < NR; ++j) acc_c = fmaf(m[j], wcv[j], acc_c);
  }

  // ---- block-reduce critic ----
#pragma unroll
  for (int off = 32; off > 0; off >>= 1) acc_c += __shfl_down(acc_c, off);
  if (x == 0) red[yg] = acc_c;
  __syncthreads();
  if (t == 0) {
    float s = bc[0];
#pragma unroll
    for (int i = 0; i < 8; ++i) s += red[i];
    out[b] = s;
  }
}

extern "C" void kernel_launch(void* const* d_in, const int* in_sizes, int n_in,
                              void* d_out, int out_size, void* d_ws, size_t ws_size,
                              hipStream_t stream) {
  (void)n_in; (void)out_size; (void)d_ws; (void)ws_size;
  const float* X   = (const float*)d_in[0];
  const float* Wh  = (const float*)d_in[1];
  const float* bh  = (const float*)d_in[2];
  const float* Wr  = (const float*)d_in[3];
  const float* Wq  = (const float*)d_in[4];
  const float* wtr = (const float*)d_in[5];
  const float* Wc  = (const float*)d_in[6];
  const float* bc  = (const float*)d_in[7];
  float* out = (float*)d_out;

  const int B = in_sizes[0] / (2 * HH * WW);   // 256
  vin_fused<<<B, 512, 0, stream>>>(X, Wh, bh, Wr, Wq, wtr, Wc, bc, out);
}

// Round 8
// 163.511 us; speedup vs baseline: 1.3269x; 1.3269x over previous
//
#include <hip/hip_runtime.h>

#define HH 64
#define WW 64
#define S  68          // padded LDS row stride (floats)
#define PH 66          // padded rows (1-px zero frame)
#define NLQ 10
#define NP  5          // channel pairs
#define NT  1024       // threads (16 waves = 4/SIMD)
#define NG  16         // row groups
#define NR  4          // rows per thread

typedef float f32x2 __attribute__((ext_vector_type(2)));

// One block per image (grid=256 = 1 block/CU). Thread t: column x=t&63, rows
// y0..y0+3 (16 row-groups).
//
// Weight/state residency war summary (R1..R14): at 512 thr the allocator
// grants only ~88-116 arch VGPRs; per-thread live state (q0[80]+win[30]+
// weights[90..180]) lands in the ACC half of the unified file -> hundreds of
// v_accvgpr_read + latency stalls per step (R12 best: 103us, VALUBusy 60%,
// ~950 instr/wave/step vs 470 ideal). Every attribute-based budget override
// failed (num_vgpr ignored, waves_per_eu ineffective, LDS pad DSE'd,
// readfirstlane -> SGPR overflow, readlane -> serialization).
//
// R15 (this): FIT IN THE BUDGET instead. 1024 threads, NR=4:
//   q0p 40 regs + win 18 + m 4 + temps ~10 = ~72 arch; only the 90
//   weight-pair regs overflow to ACC, each read ONCE per step (reused across
//   the adjacent j=0..3 block) = ~45 accvgpr reads/step, not ~480.
//   4 waves/SIMD also doubles latency hiding (R12 stalled 40% of cycles).
//   FMA cycles/SIMD conserved (same total work). pk pairing identical to
//   R12 -> bitwise-identical numerics.
__global__ __launch_bounds__(NT, 4)
void vin_fused(
    const float* __restrict__ X,    // [B,2,64,64]
    const float* __restrict__ Wh,   // [150,2,3,3]
    const float* __restrict__ bh,   // [150]
    const float* __restrict__ Wr,   // [150]
    const float* __restrict__ Wq,   // [10,1,3,3]
    const float* __restrict__ wtr,  // [10,1,3,3] transition
    const float* __restrict__ Wc,   // [4096]
    const float* __restrict__ bc,   // [1]
    float* __restrict__ out)        // [256 critic] ++ [256*40960 q]
{
  __shared__ float vb[2][PH * S];
  __shared__ float rb[PH * S];
  __shared__ float Wef[19];
  __shared__ float Wpart[152];
  __shared__ float red[NG];

  const int b  = blockIdx.x;
  const int t  = threadIdx.x;
  const int x  = t & 63;
  const int yg = t >> 6;          // 0..15
  const int y0 = yg * NR;
  const int base0 = y0 * S + x;   // top-left of 3x3 window for row y0 (padded)

  // ---- zero LDS (frames must be 0; interiors overwritten) ----
  {
    float* vbf = &vb[0][0];
    for (int i = t; i < 2 * PH * S; i += NT) vbf[i] = 0.f;
    for (int i = t; i < PH * S; i += NT) rb[i] = 0.f;
  }
  __syncthreads();

  // ---- stage X into vb interiors; collapse 150-ch conv to Wef[19] ----
  const float* Xb = X + (size_t)b * (2 * HH * WW);
  for (int i = t; i < HH * WW; i += NT) {
    const int yy = i >> 6, xx = i & 63;
    vb[0][(yy + 1) * S + xx + 1] = Xb[i];
    vb[1][(yy + 1) * S + xx + 1] = Xb[HH * WW + i];
  }
  if (t < 152) {                       // parallel collapse: 19 outputs x 8 parts
    const int i = t >> 3, part = t & 7;
    float s = 0.f;
    if (i < 18) {
      for (int c = part; c < 150; c += 8) s += Wr[c] * Wh[c * 18 + i];
    } else {
      for (int c = part; c < 150; c += 8) s += Wr[c] * bh[c];
    }
    Wpart[t] = s;
  }
  __syncthreads();
  if (t < 19) {
    float s = 0.f;
#pragma unroll
    for (int k = 0; k < 8; ++k) s += Wpart[t * 8 + k];
    Wef[t] = s;
  }
  __syncthreads();

  // ---- r = conv(X, Weff, pad=1) + beff -> rb ----
  {
    float We[19];
#pragma unroll
    for (int i = 0; i < 19; ++i) We[i] = Wef[i];
#pragma unroll
    for (int j = 0; j < NR; ++j) {
      const int tb = base0 + j * S;
      float s = We[18];
#pragma unroll
      for (int dy = 0; dy < 3; ++dy)
#pragma unroll
        for (int dx = 0; dx < 3; ++dx) {
          const int idx = tb + dy * S + dx;
          s = fmaf(vb[0][idx], We[dy * 3 + dx], s);
          s = fmaf(vb[1][idx], We[9 + dy * 3 + dx], s);
        }
      rb[tb + S + 1] = s;
    }
  }
  __syncthreads();

  // ---- q0 = conv(r, Wq, pad=1) -> q0p pairs; v_init = max_l q0 -> vb[0] ----
  f32x2 q0p[NR][NP];
  {
    f32x2 wqp[NP][9];   // q0-conv weight pairs (dead after this section)
#pragma unroll
    for (int p = 0; p < NP; ++p)
#pragma unroll
      for (int k = 0; k < 9; ++k)
        wqp[p][k] = (f32x2){ Wq[(2 * p) * 9 + k], Wq[(2 * p + 1) * 9 + k] };
#pragma unroll
    for (int j = 0; j < NR; ++j) {
      const int a = base0 + j * S;
      f32x2 acc[NP];
#pragma unroll
      for (int p = 0; p < NP; ++p) acc[p] = (f32x2){0.f, 0.f};
#pragma unroll
      for (int dy = 0; dy < 3; ++dy)
#pragma unroll
        for (int dx = 0; dx < 3; ++dx) {
          const int k = dy * 3 + dx;
          const float wv = rb[a + dy * S + dx];
          const f32x2 ws = { wv, wv };
#pragma unroll
          for (int p = 0; p < NP; ++p)
            acc[p] = __builtin_elementwise_fma(wqp[p][k], ws, acc[p]);
        }
#pragma unroll
      for (int p = 0; p < NP; ++p) q0p[j][p] = acc[p];
      f32x2 m01 = __builtin_elementwise_max(acc[0], acc[1]);
      f32x2 m23 = __builtin_elementwise_max(acc[2], acc[3]);
      m01 = __builtin_elementwise_max(m01, m23);
      m01 = __builtin_elementwise_max(m01, acc[4]);
      vb[0][base0 + (j + 1) * S + 1] = fmaxf(m01.x, m01.y);
    }
  }
  __syncthreads();

  // ---- transition weight pairs (steady-state resident) ----
  f32x2 wtp[NP][9];
#pragma unroll
  for (int p = 0; p < NP; ++p)
#pragma unroll
    for (int k = 0; k < 9; ++k)
      wtp[p][k] = (f32x2){ wtr[(2 * p) * 9 + k], wtr[(2 * p + 1) * 9 + k] };

  // ---- K-loop: q = q0 + conv(v, w); v = max_ch(q) ----
  auto step = [&](const float* __restrict__ vin, float* __restrict__ vout) {
    float win[NR + 2][3];
#pragma unroll
    for (int rr = 0; rr < NR + 2; ++rr) {
      const int a = base0 + rr * S;
      win[rr][0] = vin[a];
      win[rr][1] = vin[a + 1];
      win[rr][2] = vin[a + 2];
    }
#pragma unroll
    for (int j = 0; j < NR; ++j) {
      f32x2 acc[NP];
#pragma unroll
      for (int p = 0; p < NP; ++p) acc[p] = q0p[j][p];
#pragma unroll
      for (int dy = 0; dy < 3; ++dy)
#pragma unroll
        for (int dx = 0; dx < 3; ++dx) {
          const int k = dy * 3 + dx;
          const float wv = win[j + dy][dx];
          const f32x2 ws = { wv, wv };
#pragma unroll
          for (int p = 0; p < NP; ++p)
            acc[p] = __builtin_elementwise_fma(wtp[p][k], ws, acc[p]);
        }
      f32x2 m01 = __builtin_elementwise_max(acc[0], acc[1]);
      f32x2 m23 = __builtin_elementwise_max(acc[2], acc[3]);
      m01 = __builtin_elementwise_max(m01, m23);
      m01 = __builtin_elementwise_max(m01, acc[4]);
      vout[base0 + (j + 1) * S + 1] = fmaxf(m01.x, m01.y);
    }
    __syncthreads();
  };

#pragma unroll 1
  for (int s2 = 0; s2 < 19; ++s2) { step(vb[0], vb[1]); step(vb[1], vb[0]); }
  step(vb[0], vb[1]);   // it = 38: reads vb[0], writes vb[1]

  // ---- final iteration (it=39): emit q + critic dot ----
  float wcv[NR];
#pragma unroll
  for (int j = 0; j < NR; ++j) wcv[j] = Wc[(y0 + j) * WW + x];

  float* qo = out + 256 + (size_t)b * (NLQ * HH * WW) + y0 * WW + x;
  float acc_c = 0.f;
  {
    const float* vin = vb[1];
    float win[NR + 2][3];
#pragma unroll
    for (int rr = 0; rr < NR + 2; ++rr) {
      const int a = base0 + rr * S;
      win[rr][0] = vin[a];
      win[rr][1] = vin[a + 1];
      win[rr][2] = vin[a + 2];
    }
#pragma unroll
    for (int j = 0; j < NR; ++j) {
      f32x2 acc[NP];
#pragma unroll
      for (int p = 0; p < NP; ++p) acc[p] = q0p[j][p];
#pragma unroll
      for (int dy = 0; dy < 3; ++dy)
#pragma unroll
        for (int dx = 0; dx < 3; ++dx) {
          const int k = dy * 3 + dx;
          const float wv = win[j + dy][dx];
          const f32x2 ws = { wv, wv };
#pragma unroll
          for (int p = 0; p < NP; ++p)
            acc[p] = __builtin_elementwise_fma(wtp[p][k], ws, acc[p]);
        }
#pragma unroll
      for (int p = 0; p < NP; ++p) {
        qo[(2 * p)     * (HH * WW) + j * WW] = acc[p].x;
        qo[(2 * p + 1) * (HH * WW) + j * WW] = acc[p].y;
      }
      f32x2 m01 = __builtin_elementwise_max(acc[0], acc[1]);
      f32x2 m23 = __builtin_elementwise_max(acc[2], acc[3]);
      m01 = __builtin_elementwise_max(m01, m23);
      m01 = __builtin_elementwise_max(m01, acc[4]);
      acc_c = fmaf(fmaxf(m01.x, m01.y), wcv[j], acc_c);
    }
  }

  // ---- block-reduce critic ----
#pragma unroll
  for (int off = 32; off > 0; off >>= 1) acc_c += __shfl_down(acc_c, off);
  if (x == 0) red[yg] = acc_c;
  __syncthreads();
  if (t == 0) {
    float s = bc[0];
#pragma unroll
    for (int i = 0; i < NG; ++i) s += red[i];
    out[b] = s;
  }
}

extern "C" void kernel_launch(void* const* d_in, const int* in_sizes, int n_in,
                              void* d_out, int out_size, void* d_ws, size_t ws_size,
                              hipStream_t stream) {
  (void)n_in; (void)out_size; (void)d_ws; (void)ws_size;
  const float* X   = (const float*)d_in[0];
  const float* Wh  = (const float*)d_in[1];
  const float* bh  = (const float*)d_in[2];
  const float* Wr  = (const float*)d_in[3];
  const float* Wq  = (const float*)d_in[4];
  const float* wtr = (const float*)d_in[5];
  const float* Wc  = (const float*)d_in[6];
  const float* bc  = (const float*)d_in[7];
  float* out = (float*)d_out;

  const int B = in_sizes[0] / (2 * HH * WW);   // 256
  vin_fused<<<B, NT, 0, stream>>>(X, Wh, bh, Wr, Wq, wtr, Wc, bc, out);
}